// Round 5
// baseline (115.947 us; speedup 1.0000x reference)
//
#include <hip/hip_runtime.h>

#define NROWS 16384
#define DIM   1024          // floats per row
#define F4_PER_ROW 256      // DIM/4
#define MARGIN_F 1.0f
#define EPS_F 1e-6f

#define ROWS_PER_WAVE   2
#define WAVES_PER_BLOCK 4
#define NBLOCKS (NROWS / (ROWS_PER_WAVE * WAVES_PER_BLOCK))   // 2048

typedef float f32x4 __attribute__((ext_vector_type(4)));

// TWO rows per wave, software-pipelined at the waitcnt level:
//   issue all 24 loads (both rows) -> asm#1 materializes only row-0's 12
//   ("memory" clobber pins issue order; compiler's dataflow waitcnt pass
//   emits vmcnt(12), leaving row-1's loads IN FLIGHT) -> reduce row 0
//   (48 FMA + 48 ds_swizzle, hides row-1 latency) -> asm#2 materializes
//   row 1 -> reduce row 1.
// r4 lesson: one multi-operand "+v" asm is the only reliable way to force
// batched issue (bare "memory" fence lets FMAs hoist; per-load asms
// serialize). r3 lesson: no same-address atomics (~20ns each, serialized).
// Single Gram pass per row (exact eps expansion, absmax 0.0 in r1-r4):
//   sum_p = si^2*ni + sp^2*np - 2*si*sp*dot_ip + 2*eps*(si*Sa - sp*Sb) + D*eps^2
__global__ __launch_bounds__(256) void row_loss_kernel(
    const float* __restrict__ emb,
    const int*   __restrict__ pos_idx,
    const int*   __restrict__ neg_idx,
    float*       __restrict__ block_part)
{
    const int tid  = threadIdx.x;
    const int lane = tid & 63;
    const int wid  = tid >> 6;
    const int r0   = (blockIdx.x * WAVES_PER_BLOCK + wid) * ROWS_PER_WAVE;
    const int r1   = r0 + 1;

    const int p0 = pos_idx[r0], n0 = neg_idx[r0];   // wave-uniform -> scalar
    const int p1 = pos_idx[r1], n1 = neg_idx[r1];

    const f32x4* e4 = (const f32x4*)emb;
    const f32x4* xi0 = e4 + (size_t)r0 * F4_PER_ROW + lane;
    const f32x4* xp0 = e4 + (size_t)p0 * F4_PER_ROW + lane;
    const f32x4* xn0 = e4 + (size_t)n0 * F4_PER_ROW + lane;
    const f32x4* xi1 = e4 + (size_t)r1 * F4_PER_ROW + lane;
    const f32x4* xp1 = e4 + (size_t)p1 * F4_PER_ROW + lane;
    const f32x4* xn1 = e4 + (size_t)n1 * F4_PER_ROW + lane;

    // --- issue ALL 24 independent 16B loads (both rows) ---
    f32x4 a0 = xi0[0], a1 = xi0[64], a2 = xi0[128], a3 = xi0[192];
    f32x4 b0 = xp0[0], b1 = xp0[64], b2 = xp0[128], b3 = xp0[192];
    f32x4 c0 = xn0[0], c1 = xn0[64], c2 = xn0[128], c3 = xn0[192];
    f32x4 d0 = xi1[0], d1 = xi1[64], d2 = xi1[128], d3 = xi1[192];
    f32x4 e0 = xp1[0], e1 = xp1[64], e2 = xp1[128], e3 = xp1[192];
    f32x4 f0 = xn1[0], f1 = xn1[64], f2 = xn1[128], f3 = xn1[192];

    // asm#1: row-0 data must be materialized here; "memory" pins all 24
    // loads above this point -> compiler waits vmcnt(12), row-1 stays in flight
    asm volatile("" : "+v"(a0), "+v"(a1), "+v"(a2), "+v"(a3),
                      "+v"(b0), "+v"(b1), "+v"(b2), "+v"(b3),
                      "+v"(c0), "+v"(c1), "+v"(c2), "+v"(c3) :: "memory");

    const float de2 = (float)DIM * EPS_F * EPS_F;
    float wave_acc = 0.f;

    #define ACC(A,B,C) \
        ni  = fmaf(A.x,A.x,ni);  ni  = fmaf(A.y,A.y,ni);  ni  = fmaf(A.z,A.z,ni);  ni  = fmaf(A.w,A.w,ni);  \
        np_ = fmaf(B.x,B.x,np_); np_ = fmaf(B.y,B.y,np_); np_ = fmaf(B.z,B.z,np_); np_ = fmaf(B.w,B.w,np_); \
        nn  = fmaf(C.x,C.x,nn);  nn  = fmaf(C.y,C.y,nn);  nn  = fmaf(C.z,C.z,nn);  nn  = fmaf(C.w,C.w,nn);  \
        dip = fmaf(A.x,B.x,dip); dip = fmaf(A.y,B.y,dip); dip = fmaf(A.z,B.z,dip); dip = fmaf(A.w,B.w,dip); \
        din = fmaf(A.x,C.x,din); din = fmaf(A.y,C.y,din); din = fmaf(A.z,C.z,din); din = fmaf(A.w,C.w,din); \
        sa += (A.x + A.y) + (A.z + A.w);   \
        sb += (B.x + B.y) + (B.z + B.w);   \
        sc += (C.x + C.y) + (C.z + C.w);

    #define BFLY() \
        _Pragma("unroll") \
        for (int m = 1; m < 64; m <<= 1) { \
            ni  += __shfl_xor(ni,  m, 64); \
            np_ += __shfl_xor(np_, m, 64); \
            nn  += __shfl_xor(nn,  m, 64); \
            dip += __shfl_xor(dip, m, 64); \
            din += __shfl_xor(din, m, 64); \
            sa  += __shfl_xor(sa,  m, 64); \
            sb  += __shfl_xor(sb,  m, 64); \
            sc  += __shfl_xor(sc,  m, 64); \
        }

    #define EPILOG() \
        { \
            const float si = 1.0f / fmaxf(sqrtf(ni),  EPS_F); \
            const float sp = 1.0f / fmaxf(sqrtf(np_), EPS_F); \
            const float sn = 1.0f / fmaxf(sqrtf(nn),  EPS_F); \
            float sum_p = fmaf(si * si, ni, fmaf(sp * sp, np_, -2.f * si * sp * dip)) \
                        + 2.f * EPS_F * (si * sa - sp * sb) + de2; \
            float sum_n = fmaf(si * si, ni, fmaf(sn * sn, nn, -2.f * si * sn * din)) \
                        + 2.f * EPS_F * (si * sa - sn * sc) + de2; \
            float d_pos = sqrtf(fmaxf(sum_p, 0.f)) + EPS_F; \
            float d_neg = sqrtf(fmaxf(sum_n, 0.f)) + EPS_F; \
            float mq    = fmaxf(MARGIN_F - d_neg, EPS_F); \
            wave_acc += fmaf(d_pos, d_pos, mq * mq); \
        }

    // ---- row 0: reduce while row 1's loads fly ----
    {
        float ni = 0.f, np_ = 0.f, nn = 0.f, dip = 0.f, din = 0.f;
        float sa = 0.f, sb = 0.f, sc = 0.f;
        ACC(a0,b0,c0) ACC(a1,b1,c1) ACC(a2,b2,c2) ACC(a3,b3,c3)
        BFLY()
        EPILOG()
    }

    // asm#2: row-1 data materialization point (vmcnt(0) lands here)
    asm volatile("" : "+v"(d0), "+v"(d1), "+v"(d2), "+v"(d3),
                      "+v"(e0), "+v"(e1), "+v"(e2), "+v"(e3),
                      "+v"(f0), "+v"(f1), "+v"(f2), "+v"(f3) :: "memory");

    // ---- row 1 ----
    {
        float ni = 0.f, np_ = 0.f, nn = 0.f, dip = 0.f, din = 0.f;
        float sa = 0.f, sb = 0.f, sc = 0.f;
        ACC(d0,e0,f0) ACC(d1,e1,f1) ACC(d2,e2,f2) ACC(d3,e3,f3)
        BFLY()
        EPILOG()
    }
    #undef ACC
    #undef BFLY
    #undef EPILOG

    __shared__ float sm[WAVES_PER_BLOCK];
    if (lane == 0) sm[wid] = wave_acc;
    __syncthreads();
    if (tid == 0)
        block_part[blockIdx.x] = (sm[0] + sm[1]) + (sm[2] + sm[3]);
}

// 2048 block partials -> scalar. One block, 256 threads, 8 KiB read.
__global__ __launch_bounds__(256) void final_reduce_kernel(
    const float* __restrict__ part,
    float*       __restrict__ out)
{
    const int tid = threadIdx.x;
    const f32x4* p4 = (const f32x4*)part;   // 512 float4
    f32x4 v0 = p4[tid], v1 = p4[tid + 256];
    float s = ((v0.x + v0.y) + (v0.z + v0.w)) + ((v1.x + v1.y) + (v1.z + v1.w));
    #pragma unroll
    for (int m = 1; m < 64; m <<= 1) s += __shfl_xor(s, m, 64);

    __shared__ float sm[4];
    if ((tid & 63) == 0) sm[tid >> 6] = s;
    __syncthreads();
    if (tid == 0)
        out[0] = ((sm[0] + sm[1]) + (sm[2] + sm[3])) * (1.0f / (2.0f * (float)NROWS));
}

extern "C" void kernel_launch(void* const* d_in, const int* in_sizes, int n_in,
                              void* d_out, int out_size, void* d_ws, size_t ws_size,
                              hipStream_t stream) {
    const float* emb = (const float*)d_in[0];
    // d_in[1] = labels (unused by the loss itself)
    const int* pos = (const int*)d_in[2];
    const int* neg = (const int*)d_in[3];

    float* parts = (float*)d_ws;           // NBLOCKS floats of scratch
    float* out   = (float*)d_out;

    row_loss_kernel<<<NBLOCKS, 256, 0, stream>>>(emb, pos, neg, parts);
    final_reduce_kernel<<<1, 256, 0, stream>>>(parts, out);
}